// Round 4
// baseline (151.336 us; speedup 1.0000x reference)
//
#include <hip/hip_runtime.h>
#include <hip/hip_bf16.h>

namespace {

constexpr int kB = 2, kS = 512, kE = 1024, kH = 16, kD = 64;
constexpr int kM = kB * kS;   // 1024 rows in the 1024^3 GEMMs
constexpr int kBH = kB * kH;  // 32 (b,h) pairs
constexpr int kSP = 524;      // padded LDS score row stride (f32)

typedef short bf16x8 __attribute__((ext_vector_type(8)));
typedef float f32x4 __attribute__((ext_vector_type(4)));
typedef unsigned short u16x8 __attribute__((ext_vector_type(8)));

__device__ __forceinline__ unsigned short f2bf(float f) {
  __hip_bfloat16 h = __float2bfloat16(f);
  unsigned short u;
  __builtin_memcpy(&u, &h, 2);
  return u;
}
__device__ __forceinline__ float bf2f(unsigned short u) {
  unsigned int x = (unsigned int)u << 16;
  float f;
  __builtin_memcpy(&f, &x, 4);
  return f;
}

// ---------------- f32 -> bf16 conversion, all 7 tensors in one launch --------
__global__ void cvt7_kernel(const float* __restrict__ s0, const float* __restrict__ s1,
                            const float* __restrict__ s2, const float* __restrict__ s3,
                            const float* __restrict__ s4, const float* __restrict__ s5,
                            const float* __restrict__ s6,
                            unsigned short* __restrict__ dstBase) {
  const float* srcs[7] = {s0, s1, s2, s3, s4, s5, s6};
  const float* src = srcs[blockIdx.y];
  unsigned short* dst = dstBase + (size_t)blockIdx.y * (kM * kE);
  int i = (blockIdx.x * blockDim.x + threadIdx.x) * 4;
  float4 v = *reinterpret_cast<const float4*>(src + i);
  ushort4 o;
  o.x = f2bf(v.x); o.y = f2bf(v.y); o.z = f2bf(v.z); o.w = f2bf(v.w);
  *reinterpret_cast<ushort4*>(dst + i) = o;
}

// ---------------- generic 32x32 MFMA tile: C = A * B^T ----------------
__device__ __forceinline__ void mfma_tile_32x32(
    const unsigned short* __restrict__ A, int lda,
    const unsigned short* __restrict__ Bm, int ldb,
    int row0, int col0, int K, f32x4 acc[2][2]) {
  const int lane = threadIdx.x & 63;
  const int r = lane & 15;
  const int ko = (lane >> 4) * 8;
  const unsigned short* a0 = A + (size_t)(row0 + r) * lda + ko;
  const unsigned short* a1 = a0 + 16 * (size_t)lda;
  const unsigned short* b0 = Bm + (size_t)(col0 + r) * ldb + ko;
  const unsigned short* b1 = b0 + 16 * (size_t)ldb;
  for (int kk = 0; kk < K; kk += 32) {
    bf16x8 af0 = *reinterpret_cast<const bf16x8*>(a0 + kk);
    bf16x8 af1 = *reinterpret_cast<const bf16x8*>(a1 + kk);
    bf16x8 bg0 = *reinterpret_cast<const bf16x8*>(b0 + kk);
    bf16x8 bg1 = *reinterpret_cast<const bf16x8*>(b1 + kk);
    acc[0][0] = __builtin_amdgcn_mfma_f32_16x16x32_bf16(af0, bg0, acc[0][0], 0, 0, 0);
    acc[0][1] = __builtin_amdgcn_mfma_f32_16x16x32_bf16(af0, bg1, acc[0][1], 0, 0, 0);
    acc[1][0] = __builtin_amdgcn_mfma_f32_16x16x32_bf16(af1, bg0, acc[1][0], 0, 0, 0);
    acc[1][1] = __builtin_amdgcn_mfma_f32_16x16x32_bf16(af1, bg1, acc[1][1], 0, 0, 0);
  }
}

// ---------------- proj_q: qh [B,H,S,D], 4-wave blocks (64x64 tile) ----------
__global__ __launch_bounds__(256) void proj_q_kernel(
    const unsigned short* __restrict__ qb, const unsigned short* __restrict__ Wq,
    unsigned short* __restrict__ qh) {
  const int w = threadIdx.x >> 6;
  const int row0 = blockIdx.y * 64 + (w >> 1) * 32;
  const int col0 = blockIdx.x * 64 + (w & 1) * 32;
  f32x4 acc[2][2] = {};
  mfma_tile_32x32(qb, kE, Wq, kE, row0, col0, kE, acc);
  const int lane = threadIdx.x & 63;
#pragma unroll
  for (int ri = 0; ri < 2; ++ri)
#pragma unroll
    for (int ci = 0; ci < 2; ++ci)
#pragma unroll
      for (int r = 0; r < 4; ++r) {
        int i = row0 + 16 * ri + 4 * (lane >> 4) + r;  // b*512+s
        int j = col0 + 16 * ci + (lane & 15);          // h*64+d
        int b = i >> 9, s = i & 511, h = j >> 6, d = j & 63;
        qh[(((size_t)(b * kH + h) * kS) + s) * kD + d] = f2bf(acc[ri][ci][r]);
      }
}

// ---------------- mega: qp (high-MLP stream) + proj_k/v (MFMA) --------------
// 4608 blocks: flat%9==4 -> proj (512), else qp (4096 blocks x 4 waves,
// one (b,s,h) triple per wave, 16 independent dwordx4 loads in flight).
__global__ __launch_bounds__(256) void mega_kernel(
    const float* __restrict__ p, const unsigned short* __restrict__ qh,
    unsigned short* __restrict__ qp,
    const unsigned short* __restrict__ kb, const unsigned short* __restrict__ vb,
    const unsigned short* __restrict__ Wk, const unsigned short* __restrict__ Wv,
    unsigned short* __restrict__ kh, unsigned short* __restrict__ vhT) {
  const int flat = blockIdx.x;
  const int r9 = flat % 9;
  if (r9 == 4) {
    // ---- k/v projection: 64x64 tile, 4 waves ----
    const int pidx = flat / 9;       // 0..511
    const int which = pidx >> 8;     // 0=k, 1=v
    const int tile = pidx & 255;
    const int w = threadIdx.x >> 6;
    const int row0 = (tile >> 4) * 64 + (w >> 1) * 32;
    const int col0 = (tile & 15) * 64 + (w & 1) * 32;
    const unsigned short* A = which ? vb : kb;
    const unsigned short* W = which ? Wv : Wk;
    f32x4 acc[2][2] = {};
    mfma_tile_32x32(A, kE, W, kE, row0, col0, kE, acc);
    const int lane = threadIdx.x & 63;
#pragma unroll
    for (int ri = 0; ri < 2; ++ri)
#pragma unroll
      for (int ci = 0; ci < 2; ++ci)
#pragma unroll
        for (int r = 0; r < 4; ++r) {
          int i = row0 + 16 * ri + 4 * (lane >> 4) + r;
          int j = col0 + 16 * ci + (lane & 15);
          int b = i >> 9, s = i & 511, h = j >> 6, d = j & 63;
          unsigned short val = f2bf(acc[ri][ci][r]);
          if (which)
            vhT[(((size_t)(b * kH + h) * kD) + d) * kS + s] = val;
          else
            kh[(((size_t)(b * kH + h) * kS) + s) * kD + d] = val;
        }
  } else {
    // ---- qp: one (b,s,h) triple per wave ----
    const int qpblk = flat - flat / 9 - (r9 > 4 ? 1 : 0);  // 0..4095
    const int w = threadIdx.x >> 6;
    const int lane = threadIdx.x & 63;
    const int tid = qpblk * 4 + w;          // 0..16383
    const int g = lane >> 4, fi = lane & 15;
    const int bs = tid >> 4;                // b*512+s
    const int b = bs >> 9, s = bs & 511, h = tid & 15;

    // q row fragment for this group: q[16g .. 16g+15] (broadcast in group)
    const unsigned short* qrow =
        qh + (((size_t)(b * kH + h) * kS) + s) * kD + 16 * g;
    float qv[16];
    {
      u16x8 u0 = *reinterpret_cast<const u16x8*>(qrow);
      u16x8 u1 = *reinterpret_cast<const u16x8*>(qrow + 8);
#pragma unroll
      for (int i = 0; i < 8; ++i) {
        qv[i] = bf2f(u0[i]);
        qv[8 + i] = bf2f(u1[i]);
      }
    }
    // p slice for (b,s,h): 64x64 f32. float4 index: (16g+ei)*16 + fi
    const float4* p4 = reinterpret_cast<const float4*>(p) +
                       (size_t)tid * 1024 + g * 256 + fi;
    float4 acc = {0.f, 0.f, 0.f, 0.f};
#pragma unroll
    for (int ei = 0; ei < 16; ++ei) {
      float4 pv = p4[ei * 16];
      acc.x += qv[ei] * pv.x;
      acc.y += qv[ei] * pv.y;
      acc.z += qv[ei] * pv.z;
      acc.w += qv[ei] * pv.w;
    }
    // reduce across the 4 e-groups (lane bits 4,5)
    acc.x += __shfl_xor(acc.x, 16);
    acc.y += __shfl_xor(acc.y, 16);
    acc.z += __shfl_xor(acc.z, 16);
    acc.w += __shfl_xor(acc.w, 16);
    acc.x += __shfl_xor(acc.x, 32);
    acc.y += __shfl_xor(acc.y, 32);
    acc.z += __shfl_xor(acc.z, 32);
    acc.w += __shfl_xor(acc.w, 32);
    if (g == 0) {
      ushort4 o;
      o.x = f2bf(acc.x); o.y = f2bf(acc.y); o.z = f2bf(acc.z); o.w = f2bf(acc.w);
      *reinterpret_cast<ushort4*>(
          qp + (((size_t)(b * kH + h) * kS) + s) * kD + fi * 4) = o;
    }
  }
}

// ---------------- fused scores -> softmax -> PV -------------------------------
__global__ __launch_bounds__(256) void attn_kernel(
    const unsigned short* __restrict__ qp,
    const unsigned short* __restrict__ kh,
    const unsigned short* __restrict__ vhT,
    unsigned short* __restrict__ att) {
  __shared__ float S[32 * kSP];  // ~67 KB
  const int bh = blockIdx.y;
  const int b = bh >> 4, h = bh & 15;
  const int bx = blockIdx.x;
  const int row0 = bx * 32;
  const int ncol = row0 + 32;
  const int w = threadIdx.x >> 6;
  const int lane = threadIdx.x & 63;
  const int g = lane >> 4, c = lane & 15;

  const unsigned short* Abase = qp + (size_t)bh * kS * kD;
  const unsigned short* Kbase = kh + (size_t)bh * kS * kD;

  bf16x8 qa[2][2];
#pragma unroll
  for (int ri = 0; ri < 2; ++ri)
#pragma unroll
    for (int kk = 0; kk < 2; ++kk)
      qa[ri][kk] = *reinterpret_cast<const bf16x8*>(
          Abase + (size_t)(row0 + 16 * ri + c) * kD + kk * 32 + g * 8);

  // ---- phase 1: scores ----
  for (int ct = w; ct <= bx; ct += 4) {
    const int col0 = ct * 32;
    const unsigned short* kr0 = Kbase + (size_t)(col0 + c) * kD + g * 8;
    bf16x8 kb00 = *reinterpret_cast<const bf16x8*>(kr0);
    bf16x8 kb01 = *reinterpret_cast<const bf16x8*>(kr0 + 32);
    bf16x8 kb10 = *reinterpret_cast<const bf16x8*>(kr0 + 16 * kD);
    bf16x8 kb11 = *reinterpret_cast<const bf16x8*>(kr0 + 16 * kD + 32);
    f32x4 sacc[2][2] = {};
    sacc[0][0] = __builtin_amdgcn_mfma_f32_16x16x32_bf16(qa[0][0], kb00, sacc[0][0], 0, 0, 0);
    sacc[0][0] = __builtin_amdgcn_mfma_f32_16x16x32_bf16(qa[0][1], kb01, sacc[0][0], 0, 0, 0);
    sacc[0][1] = __builtin_amdgcn_mfma_f32_16x16x32_bf16(qa[0][0], kb10, sacc[0][1], 0, 0, 0);
    sacc[0][1] = __builtin_amdgcn_mfma_f32_16x16x32_bf16(qa[0][1], kb11, sacc[0][1], 0, 0, 0);
    sacc[1][0] = __builtin_amdgcn_mfma_f32_16x16x32_bf16(qa[1][0], kb00, sacc[1][0], 0, 0, 0);
    sacc[1][0] = __builtin_amdgcn_mfma_f32_16x16x32_bf16(qa[1][1], kb01, sacc[1][0], 0, 0, 0);
    sacc[1][1] = __builtin_amdgcn_mfma_f32_16x16x32_bf16(qa[1][0], kb10, sacc[1][1], 0, 0, 0);
    sacc[1][1] = __builtin_amdgcn_mfma_f32_16x16x32_bf16(qa[1][1], kb11, sacc[1][1], 0, 0, 0);
#pragma unroll
    for (int ri = 0; ri < 2; ++ri)
#pragma unroll
      for (int ci = 0; ci < 2; ++ci)
#pragma unroll
        for (int r = 0; r < 4; ++r) {
          int il = 16 * ri + 4 * g + r;
          int jg = col0 + 16 * ci + c;
          float val = sacc[ri][ci][r] * 0.125f;
          if (jg > row0 + il) val = -1e9f;
          S[il * kSP + jg] = val;
        }
  }
  __syncthreads();

  // ---- phase 2: softmax, rows w*8 .. w*8+7 ----
#pragma unroll
  for (int rr = 0; rr < 8; ++rr) {
    const int i = w * 8 + rr;
    float v[8];
    float m = -1e30f;
#pragma unroll
    for (int ii = 0; ii < 8; ++ii) {
      int j = lane + 64 * ii;
      v[ii] = (j < ncol) ? S[i * kSP + j] : -1e30f;
      m = fmaxf(m, v[ii]);
    }
#pragma unroll
    for (int off = 32; off; off >>= 1) m = fmaxf(m, __shfl_xor(m, off));
    float e[8], sum = 0.f;
#pragma unroll
    for (int ii = 0; ii < 8; ++ii) {
      e[ii] = __expf(v[ii] - m);
      sum += e[ii];
    }
#pragma unroll
    for (int off = 32; off; off >>= 1) sum += __shfl_xor(sum, off);
    const float inv = 1.0f / sum;
#pragma unroll
    for (int ii = 0; ii < 8; ++ii) S[i * kSP + lane + 64 * ii] = e[ii] * inv;
  }
  __syncthreads();

  // ---- phase 3: PV, wave w handles d in [16w, 16w+16) ----
  const int d0 = w * 16;
  const unsigned short* Vbase = vhT + (size_t)(bh * kD + d0 + c) * kS;
  f32x4 oacc[2] = {};
  const int nk = bx + 1;
  for (int ks = 0; ks < nk; ++ks) {
    const int kb = ks * 32;
    bf16x8 vfrag = *reinterpret_cast<const bf16x8*>(Vbase + kb + g * 8);
#pragma unroll
    for (int ri = 0; ri < 2; ++ri) {
      const float* sp = &S[(16 * ri + c) * kSP + kb + g * 8];
      float4 x0 = *reinterpret_cast<const float4*>(sp);
      float4 x1 = *reinterpret_cast<const float4*>(sp + 4);
      bf16x8 pa;
      pa[0] = (short)f2bf(x0.x); pa[1] = (short)f2bf(x0.y);
      pa[2] = (short)f2bf(x0.z); pa[3] = (short)f2bf(x0.w);
      pa[4] = (short)f2bf(x1.x); pa[5] = (short)f2bf(x1.y);
      pa[6] = (short)f2bf(x1.z); pa[7] = (short)f2bf(x1.w);
      oacc[ri] = __builtin_amdgcn_mfma_f32_16x16x32_bf16(pa, vfrag, oacc[ri], 0, 0, 0);
    }
  }
#pragma unroll
  for (int ri = 0; ri < 2; ++ri)
#pragma unroll
    for (int r = 0; r < 4; ++r) {
      int s = row0 + 16 * ri + 4 * g + r;
      int d = d0 + c;
      att[((size_t)(b * kS + s) * kE) + h * kD + d] = f2bf(oacc[ri][r]);
    }
}

// ---------------- out = att @ Wo^T (f32 output), 4-wave blocks ---------------
__global__ __launch_bounds__(256) void out_kernel(
    const unsigned short* __restrict__ att, const unsigned short* __restrict__ Wo,
    float* __restrict__ out) {
  const int w = threadIdx.x >> 6;
  const int row0 = blockIdx.y * 64 + (w >> 1) * 32;
  const int col0 = blockIdx.x * 64 + (w & 1) * 32;
  f32x4 acc[2][2] = {};
  mfma_tile_32x32(att, kE, Wo, kE, row0, col0, kE, acc);
  const int lane = threadIdx.x & 63;
#pragma unroll
  for (int ri = 0; ri < 2; ++ri)
#pragma unroll
    for (int ci = 0; ci < 2; ++ci)
#pragma unroll
      for (int r = 0; r < 4; ++r) {
        int i = row0 + 16 * ri + 4 * (lane >> 4) + r;
        int j = col0 + 16 * ci + (lane & 15);
        out[(size_t)i * kE + j] = acc[ri][ci][r];
      }
}

}  // namespace

extern "C" void kernel_launch(void* const* d_in, const int* in_sizes, int n_in,
                              void* d_out, int out_size, void* d_ws,
                              size_t ws_size, hipStream_t stream) {
  const float* q = (const float*)d_in[0];
  const float* k = (const float*)d_in[1];
  const float* v = (const float*)d_in[2];
  const float* p = (const float*)d_in[3];
  const float* Wq = (const float*)d_in[5];
  const float* Wk = (const float*)d_in[6];
  const float* Wv = (const float*)d_in[7];
  const float* Wo = (const float*)d_in[8];
  float* out = (float*)d_out;

  char* ws = (char*)d_ws;
  size_t off = 0;
  auto alloc = [&](size_t bytes) {
    void* ptr = ws + off;
    off += (bytes + 255) & ~(size_t)255;
    return ptr;
  };
  const size_t nME = (size_t)kM * kE;  // 1,048,576
  // NOTE: these 7 must stay consecutive 2MB regions (cvt7 indexes off qb).
  unsigned short* qb = (unsigned short*)alloc(nME * 2);
  unsigned short* kb = (unsigned short*)alloc(nME * 2);
  unsigned short* vb = (unsigned short*)alloc(nME * 2);
  unsigned short* Wqb = (unsigned short*)alloc(nME * 2);
  unsigned short* Wkb = (unsigned short*)alloc(nME * 2);
  unsigned short* Wvb = (unsigned short*)alloc(nME * 2);
  unsigned short* Wob = (unsigned short*)alloc(nME * 2);
  unsigned short* qhB = (unsigned short*)alloc(nME * 2);
  unsigned short* khB = (unsigned short*)alloc(nME * 2);
  unsigned short* vhTB = (unsigned short*)alloc(nME * 2);
  unsigned short* qpB = (unsigned short*)alloc(nME * 2);
  unsigned short* attB = (unsigned short*)alloc(nME * 2);

  cvt7_kernel<<<dim3(kM * kE / (256 * 4), 7), 256, 0, stream>>>(
      q, k, v, Wq, Wk, Wv, Wo, qb);

  proj_q_kernel<<<dim3(kE / 64, kM / 64), 256, 0, stream>>>(qb, Wqb, qhB);

  mega_kernel<<<4608, 256, 0, stream>>>(p, qhB, qpB, kb, vb, Wkb, Wvb, khB,
                                        vhTB);

  attn_kernel<<<dim3(kS / 32, kBH), 256, 0, stream>>>(qpB, khB, vhTB, attB);

  out_kernel<<<dim3(kE / 64, kM / 64), 256, 0, stream>>>(attB, Wob, out);
}